// Round 1
// 130.921 us; speedup vs baseline: 1.0460x; 1.0460x over previous
//
#include <hip/hip_runtime.h>
#include <hip/hip_bf16.h>
#include <cstdint>

// Problem constants: T=512 timesteps/slots, B=64 batch, E=512 embed.
#define TT 512
#define BB 64
#define EE 512

typedef short bf16x8 __attribute__((ext_vector_type(8)));   // 8 bf16 = 4 VGPRs (A/B frag)
typedef float f32x4  __attribute__((ext_vector_type(4)));   // C/D frag

// Round-half-up bf16 pack of (a -> low16, b -> high16). Differs from RNE only
// at exact ties (half-ulp); error magnitude identical.
static __device__ __forceinline__ unsigned int pack_bf16(float a, float b) {
    const unsigned ua = __float_as_uint(a) + 0x8000u;
    const unsigned ub = __float_as_uint(b) + 0x8000u;
    return (ua >> 16) | (ub & 0xffff0000u);
}

// Barrier that does NOT drain vmcnt: LDS traffic is made visible
// (lgkmcnt(0)), but in-flight global register prefetches stay outstanding.
// The compiler inserts the vmcnt wait before the first use of the loaded regs.
static __device__ __forceinline__ void barrier_lds_only() {
    asm volatile("s_waitcnt lgkmcnt(0)" ::: "memory");
    __builtin_amdgcn_s_barrier();
}

// ---------------------------------------------------------------------------
// Single fused kernel.
//   wave 0 prologue: per-batch queue scan (closed form, max-plus wave scan)
//     Q(t) = relu(Q(t-1) - u_t) + d_t,  CU(t) = sum u,  R(t) = Q(t) + CU(t)
//     -> Rs[], CUs[] in LDS (no HBM round trip, no second dispatch).
//   main loop: out[t,b,e] = sum_i C[t,i] * V[i,b,e] with
//     C[t,i] = min(relu(R_i-CU_t),1) - min(relu(R_{i-1}-CU_t),1)  (0 for i>t)
//   A-tile computed in-kernel from R/CU; B-tile = V fp32->bf16 reg transpose.
//   Triangular K-loop: m-tile MI only needs k < (MI+1)*128.
//   128m x 128n block tile, BK=32, 4 waves (2x2), 64x64 per wave.
//   B-loads software-pipelined one k-tile ahead; barriers drain LDS only.
//
// Block swizzle: id bits [2:0]=xcd, [7:3]=s(b-hi,NI), [9:8]=g.
//   MI = (g+s)&3  -> a CU's 4 resident blocks (ids spaced 256 under the
//   round-robin dispatch) get MI {0,1,2,3}: per-CU work 40 k-iters instead of
//   the previous worst case 64 (MI was constant across stride-256 groups).
//   Same (b, NI) on all 4 -> they re-read the same V columns concurrently.
// Grid: 1024 blocks x 256 threads; batch b -> XCD b%8 (V_b L2-resident).
// ---------------------------------------------------------------------------
__global__ __launch_bounds__(256) void gemm_fused_kernel(
        const float* __restrict__ V,    // [T(i)][B][E]
        const float* __restrict__ U,    // [T][B]
        const float* __restrict__ D,    // [T][B]
        float* __restrict__ out) {      // [T(t)][B][E]
    const int id  = blockIdx.x;
    const int xcd = id & 7;
    const int g   = id >> 8;            // 0..3 stride-256 dispatch group
    const int s   = (id >> 3) & 31;     // 0..31
    const int MI  = (g + s) & 3;        // balanced MI per CU
    const int b   = xcd + 8 * (s & 7);  // b % 8 == xcd
    const int n0  = (s >> 3) * 128;
    const int m0  = MI * 128;
    const int kiters = 4 * (MI + 1);    // k0 < m0 + 128

    __shared__ __align__(16) unsigned short As[128 * 40];  // [t][i] stride 40
    __shared__ __align__(16) unsigned short Bs[128 * 40];  // [e][i] stride 40
    __shared__ __align__(16) float Rs[TT];
    __shared__ __align__(16) float CUs[TT];

    const int tid  = threadIdx.x;
    const int wave = tid >> 6;
    const int lane = tid & 63;

    // A-fill: thread owns row t_l, 16 contiguous i.
    const int a_t  = tid >> 1;            // 0..127
    const int a_i0 = (tid & 1) * 16;      // 0 or 16
    // B-fill: thread owns 8k x 2e micro-tile.
    const int b_k8 = wave * 8;            // 0..24
    const int b_e2 = lane * 2;            // 0..126
    // Fragments: 2x2 waves, 64x64 per wave.
    const int wm   = (wave >> 1) * 64;
    const int wn   = (wave & 1) * 64;
    const int frow = lane & 15;
    const int quad = lane >> 4;

    const float* Vb = V + (size_t)b * EE + n0 + b_e2;   // + k*(BB*EE)

    // Prefetch k-tile 0 into registers; latency hides under the scan.
    float2 v[8];
    #pragma unroll
    for (int r = 0; r < 8; ++r)
        v[r] = *(const float2*)(Vb + (size_t)(b_k8 + r) * (BB * EE));

    // ---- In-block scan (wave 0 only): R/CU for batch b into LDS ----
    if (wave == 0) {
        float u[8], d[8];
        #pragma unroll
        for (int j = 0; j < 8; ++j) {
            u[j] = U[(lane * 8 + j) * BB + b];
            d[j] = D[(lane * 8 + j) * BB + b];
        }
        float A = 0.f, Bv = -1e30f, S = 0.f;
        #pragma unroll
        for (int j = 0; j < 8; ++j) {
            const float a = d[j] - u[j];
            Bv = fmaxf(Bv + a, d[j]);
            A += a;
            S += u[j];
        }
        #pragma unroll
        for (int off = 1; off < 64; off <<= 1) {
            const float Ap = __shfl_up(A, off);
            const float Bp = __shfl_up(Bv, off);
            const float Sp = __shfl_up(S, off);
            if (lane >= off) {
                Bv = fmaxf(Bp + A, Bv);
                A  = A + Ap;
                S  = S + Sp;
            }
        }
        float Aex = __shfl_up(A, 1), Bex = __shfl_up(Bv, 1), Sex = __shfl_up(S, 1);
        if (lane == 0) { Aex = 0.f; Bex = -1e30f; Sex = 0.f; }
        float Q  = fmaxf(Aex, Bex);
        float cu = Sex;

        float rv[8], cv[8];
        #pragma unroll
        for (int j = 0; j < 8; ++j) {
            cu += u[j];
            Q = fmaxf(Q - u[j], 0.f) + d[j];
            rv[j] = Q + cu;
            cv[j] = cu;
        }
        *(float4*)(Rs  + lane * 8)     = make_float4(rv[0], rv[1], rv[2], rv[3]);
        *(float4*)(Rs  + lane * 8 + 4) = make_float4(rv[4], rv[5], rv[6], rv[7]);
        *(float4*)(CUs + lane * 8)     = make_float4(cv[0], cv[1], cv[2], cv[3]);
        *(float4*)(CUs + lane * 8 + 4) = make_float4(cv[4], cv[5], cv[6], cv[7]);
    }
    barrier_lds_only();                   // v-prefetch stays in flight

    const float cu_t = CUs[m0 + a_t];

    f32x4 acc[4][4];
    #pragma unroll
    for (int mi = 0; mi < 4; ++mi)
        #pragma unroll
        for (int ni = 0; ni < 4; ++ni)
            acc[mi][ni] = f32x4{0.f, 0.f, 0.f, 0.f};

    for (int kk = 0; kk < kiters; ++kk) {
        const int k0 = kk * 32;

        // ---- A-fill: 16 coeffs from closed form ----
        {
            const int i = k0 + a_i0;
            const float4 r0 = *(const float4*)(Rs + i);
            const float4 r1 = *(const float4*)(Rs + i + 4);
            const float4 r2 = *(const float4*)(Rs + i + 8);
            const float4 r3 = *(const float4*)(Rs + i + 12);
            const float rv[16] = {r0.x, r0.y, r0.z, r0.w, r1.x, r1.y, r1.z, r1.w,
                                  r2.x, r2.y, r2.z, r2.w, r3.x, r3.y, r3.z, r3.w};
            const float prev = (i == 0) ? 0.f : Rs[i - 1];
            float pvp = fminf(fmaxf(prev - cu_t, 0.f), 1.f);
            float c[16];
            if (k0 < m0) {                    // strictly below diagonal: no mask
                #pragma unroll
                for (int j = 0; j < 16; ++j) {
                    const float pv = fminf(fmaxf(rv[j] - cu_t, 0.f), 1.f);
                    c[j] = pv - pvp;
                    pvp = pv;
                }
            } else {                          // diagonal tiles: zero for i > t
                const int t = m0 + a_t;
                #pragma unroll
                for (int j = 0; j < 16; ++j) {
                    const float pv = fminf(fmaxf(rv[j] - cu_t, 0.f), 1.f);
                    c[j] = (i + j <= t) ? (pv - pvp) : 0.f;
                    pvp = pv;
                }
            }
            uint4 w0, w1;
            w0.x = pack_bf16(c[0], c[1]);   w0.y = pack_bf16(c[2], c[3]);
            w0.z = pack_bf16(c[4], c[5]);   w0.w = pack_bf16(c[6], c[7]);
            w1.x = pack_bf16(c[8], c[9]);   w1.y = pack_bf16(c[10], c[11]);
            w1.z = pack_bf16(c[12], c[13]); w1.w = pack_bf16(c[14], c[15]);
            *(uint4*)(As + a_t * 40 + a_i0)     = w0;
            *(uint4*)(As + a_t * 40 + a_i0 + 8) = w1;
        }

        // ---- B-fill: pack the prefetched 8k x 2e of V, reg transpose ----
        {
            uint4 p0, p1;
            p0.x = pack_bf16(v[0].x, v[1].x); p0.y = pack_bf16(v[2].x, v[3].x);
            p0.z = pack_bf16(v[4].x, v[5].x); p0.w = pack_bf16(v[6].x, v[7].x);
            p1.x = pack_bf16(v[0].y, v[1].y); p1.y = pack_bf16(v[2].y, v[3].y);
            p1.z = pack_bf16(v[4].y, v[5].y); p1.w = pack_bf16(v[6].y, v[7].y);
            *(uint4*)(Bs + b_e2 * 40 + b_k8)       = p0;
            *(uint4*)(Bs + (b_e2 + 1) * 40 + b_k8) = p1;
        }

        // ---- Prefetch next k-tile (registers; stays in flight across
        //      both barriers, consumed by next iteration's pack) ----
        if (kk + 1 < kiters) {
            const float* vp = Vb + (size_t)((kk + 1) * 32 + b_k8) * (BB * EE);
            #pragma unroll
            for (int r = 0; r < 8; ++r)
                v[r] = *(const float2*)(vp + (size_t)r * (BB * EE));
        }

        barrier_lds_only();

        bf16x8 af[4], bf[4];
        #pragma unroll
        for (int mi = 0; mi < 4; ++mi)
            af[mi] = *(const bf16x8*)(As + (wm + mi * 16 + frow) * 40 + quad * 8);
        #pragma unroll
        for (int ni = 0; ni < 4; ++ni)
            bf[ni] = *(const bf16x8*)(Bs + (wn + ni * 16 + frow) * 40 + quad * 8);

        #pragma unroll
        for (int mi = 0; mi < 4; ++mi)
            #pragma unroll
            for (int ni = 0; ni < 4; ++ni)
                acc[mi][ni] = __builtin_amdgcn_mfma_f32_16x16x32_bf16(
                    af[mi], bf[ni], acc[mi][ni], 0, 0, 0);

        barrier_lds_only();
    }

    // Epilogue: C/D layout col=lane&15, row=quad*4+r (m89/m91 verified).
    #pragma unroll
    for (int mi = 0; mi < 4; ++mi) {
        #pragma unroll
        for (int r = 0; r < 4; ++r) {
            const int t = m0 + wm + mi * 16 + quad * 4 + r;
            float* orow = out + ((size_t)t * BB + b) * EE + n0 + wn + frow;
            #pragma unroll
            for (int ni = 0; ni < 4; ++ni)
                orow[ni * 16] = acc[mi][ni][r];
        }
    }
}

extern "C" void kernel_launch(void* const* d_in, const int* in_sizes, int n_in,
                              void* d_out, int out_size, void* d_ws, size_t ws_size,
                              hipStream_t stream) {
    const float* V = (const float*)d_in[0];   // [T,B,E]
    const float* U = (const float*)d_in[1];   // [T,B]
    const float* D = (const float*)d_in[2];   // [T,B]
    float* out = (float*)d_out;               // [T,B,E]

    gemm_fused_kernel<<<dim3(1024), dim3(256), 0, stream>>>(V, U, D, out);
}